// Round 9
// baseline (112.419 us; speedup 1.0000x reference)
//
#include <hip/hip_runtime.h>

// ConvTranspose3d (2,64,32^3) fp32 -> (2,32,66^3), stride2 pad1 outpad1 dil2 k3.
// Odd-grid MFMA: out[n,co,2dp+1,2hp+1,2wp+1] = bias[co] +
//   sum_{ci,kd,kh,kw} x[n,ci,dp+1-kd,hp+1-kh,wp+1-kw] * w[ci,co,kd,kh,kw]
// R22: split conv/expand.
//  - conv_c: R18's stage+MFMA verbatim, but stores accumulators to a dense
//    8 MB compact buffer val_ws[n][co][dp][hp][wp] (2x128-B segments per
//    instr, after the kernel's last global load). ONE barrier, no val-LDS
//    round trip, no compose.
//  - expand: 4224 blocks = (od 66) x (nco 64); blockIdx = od*64+nco so all
//    planes of one (n,co) map to one XCD (xcd = nco%8) -> planar streaming
//    writes like fillBufferAligned (which measures 6.3 TB/s). Bias planes =
//    pure float4 fill; value planes stage the 4 KB compact slab to LDS
//    (loads before the single barrier, all stores after) then write the
//    whole plane.
//  - R19/R20/R21 store-overlap variants all regressed 7-8 us -> strict
//    loads->compute->stores order everywhere, plain __syncthreads only.

#define DOUT 66
#define PL (DOUT*DOUT)                  // 4356 floats/plane
#define ROW_B 4352                      // bytes per (id,ih) LDS row
#define IDG_B (6*ROW_B)                 // 6 ih-rows per id group = 26112 B
#define VAL_OFF 131072                  // val_ws byte offset in d_ws (8 MB)

typedef _Float16 half8   __attribute__((ext_vector_type(8)));
typedef float    floatx16 __attribute__((ext_vector_type(16)));
typedef float    floatx4  __attribute__((ext_vector_type(4)));

// ---- k1: w-pack. wA[cc 4][tap 27][lane 64][8 f16]; lane=co+32*khalf ----
__global__ void __launch_bounds__(256) wprep(const float* __restrict__ w,
                                             _Float16* __restrict__ wA)
{
    int o = blockIdx.x * 256 + threadIdx.x;   // < 55296 = 216*256
    int j = o & 7;
    int tmp = o >> 3;
    int lane = tmp & 63;
    int g = tmp >> 6;
    int cc = g / 27, tap = g - cc * 27;
    int co = lane & 31, khalf = lane >> 5;
    int ci = cc * 16 + khalf * 8 + j;
    wA[o] = (_Float16)w[ci * 864 + co * 27 + tap];
}

// ---- k2: conv to compact. Stage+MFMA verbatim R18; 1 barrier ----
__global__ void __launch_bounds__(256, 2) conv_c(
    const float* __restrict__ x, const _Float16* __restrict__ wA,
    float* __restrict__ val_ws)
{
    __shared__ __align__(16) unsigned char xlds[3 * IDG_B];   // 78336 B

    const int tid  = threadIdx.x;
    const int lane = tid & 63;
    const int wv   = tid >> 6;           // wave = hp tile index

    unsigned b = blockIdx.x;             // 512: xcd(3) | hsub(1) | dp(5)
    const unsigned xcd = b & 7u;
    const int n     = (int)(xcd & 1u);
    const unsigned rest = b >> 3;
    const int hpg   = (int)((xcd >> 1) * 2 + (rest & 1u));   // 0..7
    const int dp    = (int)(rest >> 1);                      // 0..31
    const int hpb   = hpg * 4;           // hp = hpb..hpb+3

    const float* xn = x + (size_t)n * 2097152;

    // ---- staging: 18 rows (id 3 x ih 6), 1152 tasks, wave-uniform rows ----
    {
        for (int t = tid; t < 1152; t += 256) {
            const int r   = t >> 6;
            const int ccg = (t >> 3) & 7;
            const int gq  = t & 7;
            const int id_l = r / 6, ihl = r - 6 * id_l;
            const int id = dp - 1 + id_l;
            const int ih = hpb - 1 + ihl;
            unsigned char* dst = xlds + (id_l * 6 + ihl) * ROW_B
                               + ccg * 544 + (gq * 4 + 1) * 16;
            if (((unsigned)id < 32u) & ((unsigned)ih < 32u)) {
                const float* src = xn + ccg * 262144 + (id * 32 + ih) * 32 + gq * 4;
                floatx4 f[8];
                #pragma unroll
                for (int j = 0; j < 8; ++j) f[j] = *(const floatx4*)(src + j * 32768);
                #pragma unroll
                for (int m = 0; m < 4; ++m) {
                    unsigned p0 = __builtin_bit_cast(unsigned,
                        __builtin_amdgcn_cvt_pkrtz(f[0][m], f[1][m]));
                    unsigned p1 = __builtin_bit_cast(unsigned,
                        __builtin_amdgcn_cvt_pkrtz(f[2][m], f[3][m]));
                    unsigned p2 = __builtin_bit_cast(unsigned,
                        __builtin_amdgcn_cvt_pkrtz(f[4][m], f[5][m]));
                    unsigned p3 = __builtin_bit_cast(unsigned,
                        __builtin_amdgcn_cvt_pkrtz(f[6][m], f[7][m]));
                    *(uint4*)(dst + m * 16) = make_uint4(p0, p1, p2, p3);
                }
            } else {
                #pragma unroll
                for (int m = 0; m < 4; ++m)
                    *(uint4*)(dst + m * 16) = make_uint4(0, 0, 0, 0);
            }
        }
        // halo iwl 0/33: 18 rows x 8 ccg x 2 sides = 288 cells
        for (int h = tid; h < 288; h += 256) {
            const int r = h >> 4, rem = h & 15;
            const int cg = rem >> 1, side = rem & 1;
            *(uint4*)(xlds + r * ROW_B + cg * 544 + (side ? 33 * 16 : 0)) =
                make_uint4(0, 0, 0, 0);
        }
    }
    __syncthreads();                                 // B1: LDS staged

    // ---- MFMA: wave wv owns hp = hpb+wv; loop all 4 ci chunks ----
    const int wp    = lane & 31;
    const int khalf = lane >> 5;

    floatx16 acc = {};
    #pragma unroll
    for (int cc = 0; cc < 4; ++cc) {
        uint4 A[27];
        const _Float16* wl = wA + ((size_t)cc * 27 * 64 + lane) * 8;
        #pragma unroll
        for (int t = 0; t < 27; ++t) A[t] = *(const uint4*)(wl + t * 512);
        const int cb = (2 * cc + khalf) * 544 + wp * 16;
        #pragma unroll
        for (int kd = 0; kd < 3; ++kd)
        #pragma unroll
        for (int kh = 0; kh < 3; ++kh)
        #pragma unroll
        for (int kw = 0; kw < 3; ++kw) {
            const int tap = (kd * 3 + kh) * 3 + kw;
            const uint4* bp = (const uint4*)(xlds
                + ((2 - kd) * 6 + (wv + 2 - kh)) * ROW_B + cb + (2 - kw) * 16);
            acc = __builtin_amdgcn_mfma_f32_32x32x16_f16(
                __builtin_bit_cast(half8, A[tap]),
                __builtin_bit_cast(half8, bp[0]), acc, 0, 0, 0);
        }
    }

    // ---- compact store (after last global load; 2x128B segments/instr) ----
    __builtin_amdgcn_sched_barrier(0);
    {
        const int hp = hpb + wv;
        #pragma unroll
        for (int r = 0; r < 16; ++r) {
            const int co = (r & 3) + 8 * (r >> 2) + 4 * khalf;   // verified C/D map
            val_ws[((((size_t)(n * 32 + co)) * 32 + dp) * 32 + hp) * 32 + wp]
                = acc[r];
        }
    }
}

// ---- k3: expand compact -> full output (fillBuffer-shaped streaming) ----
__global__ void __launch_bounds__(256) expand(
    const float* __restrict__ val_ws, const float* __restrict__ bias,
    float* __restrict__ out)
{
    __shared__ float v[1024];            // one (n,co,dp) slab: 32hp x 32wp

    const int tid = threadIdx.x;
    const unsigned b = blockIdx.x;       // 4224 = od*64 + nco -> xcd = nco%8
    const int nco = (int)(b & 63u);
    const int od  = (int)(b >> 6);       // 0..65

    const float bv = bias[nco & 31];
    const floatx4 bb = {bv, bv, bv, bv};
    float* plane = out + ((size_t)nco * DOUT + od) * PL;

    const bool vplane = (od & 1) && (od < 65);
    if (vplane) {
        // stage 4 KB compact slab (coalesced float4), then barrier
        const float* src = val_ws + ((size_t)nco * 32 + (od >> 1)) * 1024;
        ((floatx4*)v)[tid] = ((const floatx4*)src)[tid];
        __syncthreads();
        for (int q = tid; q < 1089; q += 256) {
            const int e = 4 * q;
            const int rl0 = e / 66;
            const int ow0 = e - rl0 * 66;
            floatx4 o = bb;
            #pragma unroll
            for (int j = 0; j < 4; ++j) {
                int rr = rl0, ow = ow0 + j;
                if (ow >= 66) { ow -= 66; ++rr; }
                if ((rr & 1) && rr < 65 && (ow & 1) && ow < 64)
                    o[j] += v[(rr >> 1) * 32 + (ow >> 1)];
            }
            *(floatx4*)(plane + e) = o;
        }
    } else {
        // pure-bias plane: straight fill
        for (int q = tid; q < 1089; q += 256)
            *(floatx4*)(plane + 4 * q) = bb;
    }
}

extern "C" void kernel_launch(void* const* d_in, const int* in_sizes, int n_in,
                              void* d_out, int out_size, void* d_ws, size_t ws_size,
                              hipStream_t stream) {
    const float* x    = (const float*)d_in[0];
    const float* wgt  = (const float*)d_in[1];
    const float* bias = (const float*)d_in[2];
    float* out = (float*)d_out;
    _Float16* wA   = (_Float16*)d_ws;                  // 110592 B
    float* val_ws  = (float*)((char*)d_ws + VAL_OFF);  // 8 MB compact

    wprep<<<216, 256, 0, stream>>>(wgt, wA);
    conv_c<<<512, 256, 0, stream>>>(x, wA, val_ws);
    expand<<<4224, 256, 0, stream>>>(val_ws, bias, out);
}

// Round 10
// 109.256 us; speedup vs baseline: 1.0290x; 1.0290x over previous
//
#include <hip/hip_runtime.h>

// ConvTranspose3d (2,64,32^3) fp32 -> (2,32,66^3), stride2 pad1 outpad1 dil2 k3.
// Odd-grid MFMA: out[n,co,2dp+1,2hp+1,2wp+1] = bias[co] +
//   sum_{ci,kd,kh,kw} x[n,ci,dp+1-kd,hp+1-kh,wp+1-kw] * w[ci,co,kd,kh,kw]
// R23 = R18 (best, 102.7) with ONE change: XCD write-locality block remap.
//   b = hpg*64 + (n*32+dp)  ->  b%8 = dp%8, so all 8 hpg-blocks of one
//   (n,dp) -- which co-write the same 32 output planes -- land on ONE XCD
//   and are all simultaneously resident there (64 blocks/XCD = 64 slots).
//   Their 2112-B spans tile each plane contiguously in space AND time ->
//   per-XCD L2 write aggregation, no cross-XCD boundary-line RMW. The old
//   mapping (xcd = n | hpg-high) scattered one plane's writers over 4 XCDs.
//   Staging ih-halo reuse also becomes XCD-local.
// Everything else verbatim R18: strict loads->compute->stores, plain
// __syncthreads only (R19-R22 alternatives all regressed 7-10 us).

#define DOUT 66
#define PL (DOUT*DOUT)                  // 4356 floats/plane
#define ROW_B 4352                      // bytes per (id,ih) LDS row
#define IDG_B (6*ROW_B)                 // 6 ih-rows per id group = 26112 B

typedef _Float16 half8   __attribute__((ext_vector_type(8)));
typedef float    floatx16 __attribute__((ext_vector_type(16)));
typedef float    floatx4  __attribute__((ext_vector_type(4)));

// ---- k1: w-pack. wA[cc 4][tap 27][lane 64][8 f16]; lane=co+32*khalf ----
__global__ void __launch_bounds__(256) wprep(const float* __restrict__ w,
                                             _Float16* __restrict__ wA)
{
    int o = blockIdx.x * 256 + threadIdx.x;   // < 55296 = 216*256
    int j = o & 7;
    int tmp = o >> 3;
    int lane = tmp & 63;
    int g = tmp >> 6;
    int cc = g / 27, tap = g - cc * 27;
    int co = lane & 31, khalf = lane >> 5;
    int ci = cc * 16 + khalf * 8 + j;
    wA[o] = (_Float16)w[ci * 864 + co * 27 + tap];
}

// ---- k2: fused repack + conv, 4 hp tiles (1/wave) ----
__global__ void __launch_bounds__(256, 2) convt(
    const float* __restrict__ x, const _Float16* __restrict__ wA,
    const float* __restrict__ bias, float* __restrict__ out)
{
    __shared__ __align__(16) unsigned char xlds[3 * IDG_B];   // 78336 B

    const int tid  = threadIdx.x;
    const int lane = tid & 63;
    const int wv   = tid >> 6;           // wave = hp tile index

    // XCD write-locality decode: b = hpg*64 + (n*32 + dp); b%8 = dp%8.
    unsigned b = blockIdx.x;             // 512
    const int bq  = (int)(b & 63u);      // n*32 + dp
    const int n   = bq >> 5;
    const int dp  = bq & 31;             // 0..31
    const int hpg = (int)(b >> 6);       // 0..7
    const int hpb = hpg * 4;             // hp = hpb..hpb+3

    const float* xn = x + (size_t)n * 2097152;

    // store-role indices (R18 form)
    const int co_s = tid >> 3;           // 0..31
    const int l8   = tid & 7;
    const float bvc = bias[co_s];
    const floatx4 bb4 = {bvc, bvc, bvc, bvc};

    // ---- staging: 18 rows (id 3 x ih 6), 1152 tasks, wave-uniform rows ----
    {
        for (int t = tid; t < 1152; t += 256) {
            const int r   = t >> 6;
            const int ccg = (t >> 3) & 7;
            const int gq  = t & 7;
            const int id_l = r / 6, ihl = r - 6 * id_l;
            const int id = dp - 1 + id_l;
            const int ih = hpb - 1 + ihl;
            unsigned char* dst = xlds + (id_l * 6 + ihl) * ROW_B
                               + ccg * 544 + (gq * 4 + 1) * 16;
            if (((unsigned)id < 32u) & ((unsigned)ih < 32u)) {
                const float* src = xn + ccg * 262144 + (id * 32 + ih) * 32 + gq * 4;
                floatx4 f[8];
                #pragma unroll
                for (int j = 0; j < 8; ++j) f[j] = *(const floatx4*)(src + j * 32768);
                #pragma unroll
                for (int m = 0; m < 4; ++m) {
                    unsigned p0 = __builtin_bit_cast(unsigned,
                        __builtin_amdgcn_cvt_pkrtz(f[0][m], f[1][m]));
                    unsigned p1 = __builtin_bit_cast(unsigned,
                        __builtin_amdgcn_cvt_pkrtz(f[2][m], f[3][m]));
                    unsigned p2 = __builtin_bit_cast(unsigned,
                        __builtin_amdgcn_cvt_pkrtz(f[4][m], f[5][m]));
                    unsigned p3 = __builtin_bit_cast(unsigned,
                        __builtin_amdgcn_cvt_pkrtz(f[6][m], f[7][m]));
                    *(uint4*)(dst + m * 16) = make_uint4(p0, p1, p2, p3);
                }
            } else {
                #pragma unroll
                for (int m = 0; m < 4; ++m)
                    *(uint4*)(dst + m * 16) = make_uint4(0, 0, 0, 0);
            }
        }
        // halo iwl 0/33: 18 rows x 8 ccg x 2 sides = 288 cells
        for (int h = tid; h < 288; h += 256) {
            const int r = h >> 4, rem = h & 15;
            const int cg = rem >> 1, side = rem & 1;
            *(uint4*)(xlds + r * ROW_B + cg * 544 + (side ? 33 * 16 : 0)) =
                make_uint4(0, 0, 0, 0);
        }
    }
    __syncthreads();                                 // B1: LDS staged

    // ---- MFMA: wave wv owns hp = hpb+wv; loop all 4 ci chunks ----
    const int wp    = lane & 31;
    const int khalf = lane >> 5;

    floatx16 acc = {};
    #pragma unroll
    for (int cc = 0; cc < 4; ++cc) {
        uint4 A[27];
        const _Float16* wl = wA + ((size_t)cc * 27 * 64 + lane) * 8;
        #pragma unroll
        for (int t = 0; t < 27; ++t) A[t] = *(const uint4*)(wl + t * 512);
        const int cb = (2 * cc + khalf) * 544 + wp * 16;
        #pragma unroll
        for (int kd = 0; kd < 3; ++kd)
        #pragma unroll
        for (int kh = 0; kh < 3; ++kh)
        #pragma unroll
        for (int kw = 0; kw < 3; ++kw) {
            const int tap = (kd * 3 + kh) * 3 + kw;
            const uint4* bp = (const uint4*)(xlds
                + ((2 - kd) * 6 + (wv + 2 - kh)) * ROW_B + cb + (2 - kw) * 16);
            acc = __builtin_amdgcn_mfma_f32_32x32x16_f16(
                __builtin_bit_cast(half8, A[tap]),
                __builtin_bit_cast(half8, bp[0]), acc, 0, 0, 0);
        }
    }

    // ---- vals to LDS: val[hp_local 4][co 32][wp 32 +pad] ----
    __syncthreads();                                 // B2: MFMA reads done
    float* val = (float*)xlds;                       // 4*32*33*4 = 16896 B
    #pragma unroll
    for (int r = 0; r < 16; ++r) {
        const int co = (r & 3) + 8 * (r >> 2) + 4 * khalf;   // verified C/D map
        val[((size_t)wv * 32 + co) * 33 + wp] = acc[r];
    }
    __syncthreads();                                 // B3: vals visible

    // ======== ALL global stores below this line (drain only at endpgm) ====

    // ---- odd-plane span store: 8 rows (2112 B) per co, values interleaved ----
    {
        float* base = out + ((size_t)(n * 32 + co_s) * DOUT + 2 * dp + 1) * PL
                      + 8 * hpg * DOUT;
        #pragma unroll
        for (int p = 0; p < 17; ++p) {
            const int q = l8 + 8 * p;
            if (q < 132) {
                floatx4 o;
                #pragma unroll
                for (int j = 0; j < 4; ++j) {
                    const int e = 4 * q + j;          // 0..527
                    const int rl = e / 66;            // span row 0..7
                    const int ow = e - rl * 66;
                    float v = bvc;
                    if ((rl & 1) && (ow & 1) && ow < 65)
                        v += val[(((rl >> 1) * 32) + co_s) * 33 + (ow >> 1)];
                    o[j] = v;
                }
                *(floatx4*)(base + 4 * q) = o;
            }
        }
        if (hpg == 7) {                               // tail rows 64,65: bias only
            for (int p = 0; p < 5; ++p) {
                const int q = 132 + l8 + 8 * p;
                if (q < 165) *(floatx4*)(base + 4 * q) = bb4;
            }
        }
    }

    // ---- even-plane bias span (+ planes 64/65 at dp31) ----
    {
        const int nq = (hpg == 7) ? 165 : 132;       // float4s in span
        float* eb = out + ((size_t)(n * 32 + co_s) * DOUT + 2 * dp) * PL
                    + 8 * hpg * DOUT;
        for (int q = l8; q < nq; q += 8) *(floatx4*)(eb + 4 * q) = bb4;
        if (dp == 31) {
            float* p64 = out + ((size_t)(n * 32 + co_s) * DOUT + 64) * PL
                         + 8 * hpg * DOUT;
            for (int q = l8; q < nq; q += 8) *(floatx4*)(p64 + 4 * q) = bb4;
            float* p65 = p64 + PL;
            for (int q = l8; q < nq; q += 8) *(floatx4*)(p65 + 4 * q) = bb4;
        }
    }
}

extern "C" void kernel_launch(void* const* d_in, const int* in_sizes, int n_in,
                              void* d_out, int out_size, void* d_ws, size_t ws_size,
                              hipStream_t stream) {
    const float* x    = (const float*)d_in[0];
    const float* wgt  = (const float*)d_in[1];
    const float* bias = (const float*)d_in[2];
    float* out = (float*)d_out;
    _Float16* wA = (_Float16*)d_ws;      // 110592 B

    wprep<<<216, 256, 0, stream>>>(wgt, wA);
    convt<<<512, 256, 0, stream>>>(x, wA, bias, out);
}